// Round 1
// baseline (529.202 us; speedup 1.0000x reference)
//
#include <hip/hip_runtime.h>

// XConv fused kernel, fp32. Config fixed by harness:
#define NPTS   16384   // N*P
#define KNBR   16      // K neighbors
#define CMID   64
#define CIN    64
#define CCAT   128
#define KK     256
#define CDW    512     // C_CAT * DM
#define COUT   128
#define MPB    8       // points per block
#define NTHR   256

__device__ __forceinline__ float elu_f(float x) {
    return x > 0.f ? x : (__expf(x) - 1.f);
}

__global__ __launch_bounds__(NTHR, 2)
void xconv_kernel(const float* __restrict__ rep_pt,
                  const float* __restrict__ pts,
                  const float* __restrict__ fts,
                  const float* __restrict__ w1,  const float* __restrict__ b1,
                  const float* __restrict__ w2,  const float* __restrict__ b2,
                  const float* __restrict__ wc1, const float* __restrict__ bc1,
                  const float* __restrict__ wx1, const float* __restrict__ bx1,
                  const float* __restrict__ wx2, const float* __restrict__ bx2,
                  const float* __restrict__ wdw, const float* __restrict__ bdw,
                  const float* __restrict__ wpw, const float* __restrict__ bpw,
                  const float* __restrict__ bn_gamma, const float* __restrict__ bn_beta,
                  const float* __restrict__ bn_mean,  const float* __restrict__ bn_var,
                  float* __restrict__ out)
{
    // LDS: 1.5 + 32 + 8 + 16 = 57.5 KB  -> 2 blocks/CU
    __shared__ __align__(16) float s_ptsl[MPB][KNBR * 3];   // localized pts
    __shared__ __align__(16) float s_h[MPB][KNBR][CMID];    // lifted features h2
    __shared__ __align__(16) float s_x[MPB][KK];            // X0 -> X1 -> X2 in place
    __shared__ __align__(16) float s_dw[MPB][CDW];          // depthwise output

    const int t   = threadIdx.x;
    const int gp0 = blockIdx.x * MPB;   // first global point of this block

    // ---------------- Phase A: pts_local into LDS ----------------
    for (int idx = t; idx < MPB * KNBR * 3; idx += NTHR) {
        int m = idx / 48, r = idx - m * 48;
        int k = r / 3,    d = r - k * 3;
        int gp = gp0 + m;
        s_ptsl[m][r] = pts[(gp * KNBR + k) * 3 + d] - rep_pt[gp * 3 + d];
    }
    __syncthreads();

    // ---------------- Phase B: h = elu(elu(ptsl@w1+b1)@w2+b2) ----------------
    {
        int pair = t >> 1, ch = t & 1;        // 128 (m,k) pairs, 2 threads split c-range
        int m = pair >> 4, k = pair & 15;
        float p0 = s_ptsl[m][k * 3 + 0];
        float p1 = s_ptsl[m][k * 3 + 1];
        float p2 = s_ptsl[m][k * 3 + 2];
        float h1[CMID];
#pragma unroll
        for (int c = 0; c < CMID; c++) {
            float v = fmaf(p0, w1[c], fmaf(p1, w1[CMID + c], fmaf(p2, w1[2 * CMID + c], b1[c])));
            h1[c] = elu_f(v);
        }
        int cbase = ch * 32;
        for (int cg = 0; cg < 32; cg += 4) {
            int c0 = cbase + cg;
            float a0 = b2[c0 + 0], a1 = b2[c0 + 1], a2 = b2[c0 + 2], a3 = b2[c0 + 3];
#pragma unroll
            for (int j = 0; j < CMID; j++) {
                float4 wv = *(const float4*)&w2[j * CMID + c0];
                float hv = h1[j];
                a0 = fmaf(hv, wv.x, a0);
                a1 = fmaf(hv, wv.y, a1);
                a2 = fmaf(hv, wv.z, a2);
                a3 = fmaf(hv, wv.w, a3);
            }
            s_h[m][k][c0 + 0] = elu_f(a0);
            s_h[m][k][c0 + 1] = elu_f(a1);
            s_h[m][k][c0 + 2] = elu_f(a2);
            s_h[m][k][c0 + 3] = elu_f(a3);
        }
    }
    __syncthreads();

    // ---------------- Phase C: X0 = elu(einsum(ptsl, wc1) + bc1) ----------------
    {
        int o = t;                 // one output channel per thread (256)
        float wreg[48];            // wc1[o][d][k], d-major: wreg[d*16+k]
#pragma unroll
        for (int q = 0; q < 12; q++) {
            float4 wv = *(const float4*)&wc1[o * 48 + q * 4];
            wreg[q * 4 + 0] = wv.x; wreg[q * 4 + 1] = wv.y;
            wreg[q * 4 + 2] = wv.z; wreg[q * 4 + 3] = wv.w;
        }
        float bo = bc1[o];
#pragma unroll 1
        for (int m = 0; m < MPB; m++) {
            float acc = bo;
#pragma unroll
            for (int q = 0; q < 12; q++) {
                float4 pv = *(const float4*)&s_ptsl[m][q * 4];  // flat f = k*3+d
                float pe0 = pv.x, pe1 = pv.y, pe2 = pv.z, pe3 = pv.w;
                // weight index for flat f: (f%3)*16 + f/3  (all compile-time)
                acc = fmaf(pe0, wreg[((q * 4 + 0) % 3) * 16 + (q * 4 + 0) / 3], acc);
                acc = fmaf(pe1, wreg[((q * 4 + 1) % 3) * 16 + (q * 4 + 1) / 3], acc);
                acc = fmaf(pe2, wreg[((q * 4 + 2) % 3) * 16 + (q * 4 + 2) / 3], acc);
                acc = fmaf(pe3, wreg[((q * 4 + 3) % 3) * 16 + (q * 4 + 3) / 3], acc);
            }
            s_x[m][o] = elu_f(acc);
        }
    }
    __syncthreads();

    // ---------------- Phase D: X1 = elu(X0 @ wx1 + bx1), in place ----------------
    {
        int o = t;
        float acc[MPB];
        float bo = bx1[o];
#pragma unroll
        for (int mi = 0; mi < MPB; mi++) acc[mi] = bo;
        for (int j = 0; j < KK; j += 4) {
            float wa = wx1[(j + 0) * KK + o];
            float wb = wx1[(j + 1) * KK + o];
            float wc = wx1[(j + 2) * KK + o];
            float wd = wx1[(j + 3) * KK + o];
#pragma unroll
            for (int mi = 0; mi < MPB; mi++) {
                float4 xv = *(const float4*)&s_x[mi][j];
                acc[mi] = fmaf(xv.x, wa, acc[mi]);
                acc[mi] = fmaf(xv.y, wb, acc[mi]);
                acc[mi] = fmaf(xv.z, wc, acc[mi]);
                acc[mi] = fmaf(xv.w, wd, acc[mi]);
            }
        }
        __syncthreads();   // all reads of X0 done
#pragma unroll
        for (int mi = 0; mi < MPB; mi++) s_x[mi][o] = elu_f(acc[mi]);
    }
    __syncthreads();

    // ---------------- Phase E: X2 = X1 @ wx2 + bx2 (no act), in place ----------------
    {
        int o = t;
        float acc[MPB];
        float bo = bx2[o];
#pragma unroll
        for (int mi = 0; mi < MPB; mi++) acc[mi] = bo;
        for (int j = 0; j < KK; j += 4) {
            float wa = wx2[(j + 0) * KK + o];
            float wb = wx2[(j + 1) * KK + o];
            float wc = wx2[(j + 2) * KK + o];
            float wd = wx2[(j + 3) * KK + o];
#pragma unroll
            for (int mi = 0; mi < MPB; mi++) {
                float4 xv = *(const float4*)&s_x[mi][j];
                acc[mi] = fmaf(xv.x, wa, acc[mi]);
                acc[mi] = fmaf(xv.y, wb, acc[mi]);
                acc[mi] = fmaf(xv.z, wc, acc[mi]);
                acc[mi] = fmaf(xv.w, wd, acc[mi]);
            }
        }
        __syncthreads();
#pragma unroll
        for (int mi = 0; mi < MPB; mi++) s_x[mi][o] = acc[mi];
    }
    __syncthreads();

    // ---------------- Phase F: fts_X = X2 @ fts_cat, then depthwise ----------------
    {
        int c  = t & 127;          // channel of fts_cat
        int mg = t >> 7;           // 0..1 ; each thread does 4 points
#pragma unroll 1
        for (int ml = 0; ml < 4; ml++) {
            int m  = mg * 4 + ml;            // wave-uniform
            int gp = gp0 + m;
            float fc[KNBR];
            if (c < CIN) {                   // whole wave takes same side
#pragma unroll
                for (int j = 0; j < KNBR; j++) fc[j] = s_h[m][j][c];
            } else {
#pragma unroll
                for (int j = 0; j < KNBR; j++) fc[j] = fts[(gp * KNBR + j) * CIN + (c - CIN)];
            }
            float fXr[KNBR];
#pragma unroll
            for (int i = 0; i < KNBR; i++) {
                float a = 0.f;
#pragma unroll
                for (int j = 0; j < KNBR; j += 4) {
                    float4 xv = *(const float4*)&s_x[m][i * KNBR + j];
                    a = fmaf(xv.x, fc[j + 0], a);
                    a = fmaf(xv.y, fc[j + 1], a);
                    a = fmaf(xv.z, fc[j + 2], a);
                    a = fmaf(xv.w, fc[j + 3], a);
                }
                fXr[i] = a;
            }
            float dwv[4];
#pragma unroll
            for (int d = 0; d < 4; d++) {
                float a = bdw[c * 4 + d];
#pragma unroll
                for (int k = 0; k < KNBR; k += 4) {
                    float4 wv = *(const float4*)&wdw[c * 64 + d * 16 + k];
                    a = fmaf(fXr[k + 0], wv.x, a);
                    a = fmaf(fXr[k + 1], wv.y, a);
                    a = fmaf(fXr[k + 2], wv.z, a);
                    a = fmaf(fXr[k + 3], wv.w, a);
                }
                dwv[d] = a;
            }
            *(float4*)&s_dw[m][c * 4] = make_float4(dwv[0], dwv[1], dwv[2], dwv[3]);
        }
    }
    __syncthreads();

    // ---------------- Phase G: pointwise + ELU + BatchNorm ----------------
    {
        int co = t & 127;
        int mg = t >> 7;
        float acc[4];
        float bo = bpw[co];
#pragma unroll
        for (int mi = 0; mi < 4; mi++) acc[mi] = bo;
        for (int q = 0; q < CDW; q += 4) {
            float wa = wpw[(q + 0) * COUT + co];
            float wb = wpw[(q + 1) * COUT + co];
            float wc = wpw[(q + 2) * COUT + co];
            float wd = wpw[(q + 3) * COUT + co];
#pragma unroll
            for (int mi = 0; mi < 4; mi++) {
                int m = mg * 4 + mi;
                float4 dv = *(const float4*)&s_dw[m][q];
                acc[mi] = fmaf(dv.x, wa, acc[mi]);
                acc[mi] = fmaf(dv.y, wb, acc[mi]);
                acc[mi] = fmaf(dv.z, wc, acc[mi]);
                acc[mi] = fmaf(dv.w, wd, acc[mi]);
            }
        }
        float scale = bn_gamma[co] * rsqrtf(bn_var[co] + 1e-5f);
        float shift = bn_beta[co] - bn_mean[co] * scale;
#pragma unroll
        for (int mi = 0; mi < 4; mi++) {
            int m = mg * 4 + mi;
            float y = elu_f(acc[mi]);
            out[(gp0 + m) * COUT + co] = fmaf(y, scale, shift);
        }
    }
}

extern "C" void kernel_launch(void* const* d_in, const int* in_sizes, int n_in,
                              void* d_out, int out_size, void* d_ws, size_t ws_size,
                              hipStream_t stream) {
    const float* rep_pt   = (const float*)d_in[0];
    const float* pts      = (const float*)d_in[1];
    const float* fts      = (const float*)d_in[2];
    const float* w1       = (const float*)d_in[3];
    const float* b1       = (const float*)d_in[4];
    const float* w2       = (const float*)d_in[5];
    const float* b2       = (const float*)d_in[6];
    const float* wc1      = (const float*)d_in[7];
    const float* bc1      = (const float*)d_in[8];
    const float* wx1      = (const float*)d_in[9];
    const float* bx1      = (const float*)d_in[10];
    const float* wx2      = (const float*)d_in[11];
    const float* bx2      = (const float*)d_in[12];
    const float* wdw      = (const float*)d_in[13];
    const float* bdw      = (const float*)d_in[14];
    const float* wpw      = (const float*)d_in[15];
    const float* bpw      = (const float*)d_in[16];
    const float* bn_gamma = (const float*)d_in[17];
    const float* bn_beta  = (const float*)d_in[18];
    const float* bn_mean  = (const float*)d_in[19];
    const float* bn_var   = (const float*)d_in[20];
    float* out = (float*)d_out;

    dim3 grid(NPTS / MPB);   // 2048 blocks
    dim3 block(NTHR);
    xconv_kernel<<<grid, block, 0, stream>>>(
        rep_pt, pts, fts, w1, b1, w2, b2, wc1, bc1, wx1, bx1, wx2, bx2,
        wdw, bdw, wpw, bpw, bn_gamma, bn_beta, bn_mean, bn_var, out);
}

// Round 3
// 205.483 us; speedup vs baseline: 2.5754x; 2.5754x over previous
//
#include <hip/hip_runtime.h>

#define NPTS 16384
#define MPB  16
#define NTHR 256
#define WS_NEEDED 401408u

typedef __attribute__((ext_vector_type(8))) short bf16x8;
typedef __attribute__((ext_vector_type(4))) float f32x4;

__device__ __forceinline__ unsigned short f2bf(float x) {
    unsigned u = __float_as_uint(x);
    return (unsigned short)((u + 0x7FFFu + ((u >> 16) & 1u)) >> 16);
}
__device__ __forceinline__ float bf2f(unsigned short h) {
    return __uint_as_float(((unsigned)h) << 16);
}
__device__ __forceinline__ float elu_f(float x) {
    return x > 0.f ? x : (__expf(x) - 1.f);
}

// Gather one 16x16x32 B-fragment directly from a row-major fp32 matrix W[K][N].
// lane l holds B[kt*32 + (l>>4)*8 + j][nt*16 + (l&15)], j=0..7
__device__ __forceinline__ bf16x8 load_bfrag(const float* __restrict__ W, int N,
                                             int kt, int nt, int lane) {
    int k0  = kt * 32 + ((lane >> 4) << 3);
    int col = nt * 16 + (lane & 15);
    const float* s = W + k0 * N + col;
    bf16x8 r;
#pragma unroll
    for (int j = 0; j < 8; j++) r[j] = (short)f2bf(s[j * N]);
    return r;
}

// ---------------- prep: pack w2 / wx1 / wx2 / wpw into bf16 B-fragments ----
// frag order: w2 [kt*4+nt] (8), wx1 [kt*16+nt] (128), wx2 (128), wpw [kt*8+nt] (128)
// dst layout: [frag][lane][8] bf16  => 392 frags * 1KB = 392KB
__global__ void pack_weights(const float* __restrict__ w2,
                             const float* __restrict__ wx1,
                             const float* __restrict__ wx2,
                             const float* __restrict__ wpw,
                             unsigned short* __restrict__ dst) {
    int gid  = blockIdx.x * 256 + threadIdx.x;   // 98*256 = 25088 = 392*64
    int frag = gid >> 6, lane = gid & 63;
    const float* src; int N, fl;
    if      (frag <   8) { src = w2;  N =  64; fl = frag;       }
    else if (frag < 136) { src = wx1; N = 256; fl = frag - 8;   }
    else if (frag < 264) { src = wx2; N = 256; fl = frag - 136; }
    else                 { src = wpw; N = 128; fl = frag - 264; }
    int NT  = N >> 4;
    int kt  = fl / NT, nt = fl - kt * NT;
    int k0  = kt * 32 + (lane >> 4) * 8;
    int col = nt * 16 + (lane & 15);
    const float* s = src + k0 * N + col;
    unsigned v[4];
#pragma unroll
    for (int u = 0; u < 4; u++) {
        unsigned lo = f2bf(s[(2 * u) * N]);
        unsigned hi = f2bf(s[(2 * u + 1) * N]);
        v[u] = lo | (hi << 16);
    }
    *(uint4*)&dst[gid * 8] = make_uint4(v[0], v[1], v[2], v[3]);
}

// ---------------- main fused kernel -----------------------------------------
template <bool PACKED>
__global__ __launch_bounds__(NTHR, 2)
void xconv_main(const float* __restrict__ rep_pt, const float* __restrict__ pts,
                const float* __restrict__ fts,
                const float* __restrict__ w1,  const float* __restrict__ b1,
                const float* __restrict__ w2,  const float* __restrict__ b2,
                const float* __restrict__ wc1, const float* __restrict__ bc1,
                const float* __restrict__ wx1, const float* __restrict__ bx1,
                const float* __restrict__ wx2, const float* __restrict__ bx2,
                const float* __restrict__ wdw, const float* __restrict__ bdw,
                const float* __restrict__ wpw, const float* __restrict__ bpw,
                const float* __restrict__ bn_gamma, const float* __restrict__ bn_beta,
                const float* __restrict__ bn_mean,  const float* __restrict__ bn_var,
                const unsigned short* __restrict__ wpack,
                float* __restrict__ out) {
    __shared__ __align__(16) char smem[62720];
    float*          s_ptsl = (float*)smem;                          // [16][48]
    unsigned short* s_h2   = (unsigned short*)(smem + 3072);        // [256][64]
    unsigned short* s_h1   = (unsigned short*)(smem + 35840);       // [128][72]
    unsigned short* s_x0   = (unsigned short*)(smem + 35840);       // [16][264]
    unsigned short* s_x1   = (unsigned short*)(smem + 44288);       // [16][264]
    unsigned short* s_dw   = (unsigned short*)(smem + 35840);       // [16][520]
    unsigned short* s_x2   = (unsigned short*)(smem + 54272);       // [16][264]

    const int t    = threadIdx.x;
    const int lane = t & 63;
    const int w    = t >> 6;
    const int gp0  = blockIdx.x * MPB;

    // ---- Phase A: pts_local -> LDS ----
    for (int idx = t; idx < MPB * 48; idx += NTHR) {
        int m = idx / 48, r = idx - m * 48;
        int k = r / 3,    d = r - k * 3;
        int gp = gp0 + m;
        s_ptsl[idx] = pts[(gp * 16 + k) * 3 + d] - rep_pt[gp * 3 + d];
    }
    __syncthreads();

    // ---- Phase B: h1 (VALU, K=3) then h2 = elu(h1@w2+b2) via MFMA, 2 rounds ----
    for (int R = 0; R < 2; R++) {
        {   // h1 half: 2 threads per row, 32 channels each
            int lr  = t >> 1;
            int row = 128 * R + lr;           // global row = m*16+k
            int m = row >> 4, k = row & 15;
            float p0 = s_ptsl[m * 48 + k * 3 + 0];
            float p1 = s_ptsl[m * 48 + k * 3 + 1];
            float p2 = s_ptsl[m * 48 + k * 3 + 2];
            int cb = (t & 1) * 32;
#pragma unroll
            for (int cc = 0; cc < 4; cc++) {
                unsigned v[4];
#pragma unroll
                for (int u = 0; u < 4; u++) {
                    int c0 = cb + cc * 8 + u * 2;
                    float a  = fmaf(p0, w1[c0],       fmaf(p1, w1[64 + c0],     fmaf(p2, w1[128 + c0],     b1[c0])));
                    float bb = fmaf(p0, w1[c0 + 1],   fmaf(p1, w1[64 + c0 + 1], fmaf(p2, w1[128 + c0 + 1], b1[c0 + 1])));
                    v[u] = (unsigned)f2bf(elu_f(a)) | ((unsigned)f2bf(elu_f(bb)) << 16);
                }
                *(uint4*)&s_h1[lr * 72 + cb + cc * 8] = make_uint4(v[0], v[1], v[2], v[3]);
            }
        }
        __syncthreads();
        {   // h2 MFMA: local row-tiles, K=64 (2 kt), N=64 (4 nt)
            const bf16x8* wp = (const bf16x8*)wpack;   // w2 frags at base 0
            bf16x8 Bf[8];
#pragma unroll
            for (int f = 0; f < 8; f++) {
                if (PACKED) Bf[f] = wp[f * 64 + lane];
                else        Bf[f] = load_bfrag(w2, 64, f >> 2, f & 3, lane);
            }
            float bias[4];
#pragma unroll
            for (int nt = 0; nt < 4; nt++) bias[nt] = b2[nt * 16 + (lane & 15)];
#pragma unroll
            for (int i = 0; i < 2; i++) {
                int rtl = w * 2 + i;
                int g0  = (8 * R + rtl) * 16;
                bf16x8 a0 = *(const bf16x8*)&s_h1[(rtl * 16 + (lane & 15)) * 72 + 0  + (lane >> 4) * 8];
                bf16x8 a1 = *(const bf16x8*)&s_h1[(rtl * 16 + (lane & 15)) * 72 + 32 + (lane >> 4) * 8];
#pragma unroll
                for (int nt = 0; nt < 4; nt++) {
                    f32x4 acc = {bias[nt], bias[nt], bias[nt], bias[nt]};
                    acc = __builtin_amdgcn_mfma_f32_16x16x32_bf16(a0, Bf[0 * 4 + nt], acc, 0, 0, 0);
                    acc = __builtin_amdgcn_mfma_f32_16x16x32_bf16(a1, Bf[1 * 4 + nt], acc, 0, 0, 0);
#pragma unroll
                    for (int r = 0; r < 4; r++) {
                        int krow = (lane >> 4) * 4 + r;
                        s_h2[(g0 + krow) * 64 + nt * 16 + (lane & 15)] = f2bf(elu_f(acc[r]));
                    }
                }
            }
        }
        __syncthreads();
    }

    // ---- Phase C: X0 = elu(ptsl einsum wc1 + bc1) (VALU), write bf16 A-layout ----
    {
        float wreg[48];                       // wc1[o][d][k] -> wreg[d*16+k]
#pragma unroll
        for (int q = 0; q < 12; q++) {
            float4 wv = *(const float4*)&wc1[t * 48 + q * 4];
            wreg[q * 4 + 0] = wv.x; wreg[q * 4 + 1] = wv.y;
            wreg[q * 4 + 2] = wv.z; wreg[q * 4 + 3] = wv.w;
        }
        float bo = bc1[t];
#pragma unroll 1
        for (int m = 0; m < MPB; m++) {
            float acc = bo;
#pragma unroll
            for (int q = 0; q < 12; q++) {
                float4 pv = *(const float4*)&s_ptsl[m * 48 + q * 4];   // flat f = k*3+d
                acc = fmaf(pv.x, wreg[((q * 4 + 0) % 3) * 16 + (q * 4 + 0) / 3], acc);
                acc = fmaf(pv.y, wreg[((q * 4 + 1) % 3) * 16 + (q * 4 + 1) / 3], acc);
                acc = fmaf(pv.z, wreg[((q * 4 + 2) % 3) * 16 + (q * 4 + 2) / 3], acc);
                acc = fmaf(pv.w, wreg[((q * 4 + 3) % 3) * 16 + (q * 4 + 3) / 3], acc);
            }
            s_x0[m * 264 + t] = f2bf(elu_f(acc));
        }
    }
    __syncthreads();

    // ---- Phase D: X1 = elu(X0 @ wx1 + bx1), MFMA, M=16,N=256,K=256 ----
    {
        const bf16x8* wp = (const bf16x8*)wpack + 512;  // wx1
        f32x4 acc[4];
#pragma unroll
        for (int q = 0; q < 4; q++) {
            float bv = bx1[(w * 4 + q) * 16 + (lane & 15)];
            acc[q] = (f32x4){bv, bv, bv, bv};
        }
#pragma unroll
        for (int kt = 0; kt < 8; kt++) {
            bf16x8 a = *(const bf16x8*)&s_x0[(lane & 15) * 264 + kt * 32 + (lane >> 4) * 8];
#pragma unroll
            for (int q = 0; q < 4; q++) {
                int nt = w * 4 + q;
                bf16x8 b;
                if (PACKED) b = wp[(kt * 16 + nt) * 64 + lane];
                else        b = load_bfrag(wx1, 256, kt, nt, lane);
                acc[q] = __builtin_amdgcn_mfma_f32_16x16x32_bf16(a, b, acc[q], 0, 0, 0);
            }
        }
#pragma unroll
        for (int q = 0; q < 4; q++) {
            int nt = w * 4 + q;
#pragma unroll
            for (int r = 0; r < 4; r++) {
                int m = (lane >> 4) * 4 + r;
                s_x1[m * 264 + nt * 16 + (lane & 15)] = f2bf(elu_f(acc[q][r]));
            }
        }
    }
    __syncthreads();

    // ---- Phase E: X2 = X1 @ wx2 + bx2 (no act), MFMA ----
    {
        const bf16x8* wp = (const bf16x8*)wpack + 8704;  // wx2
        f32x4 acc[4];
#pragma unroll
        for (int q = 0; q < 4; q++) {
            float bv = bx2[(w * 4 + q) * 16 + (lane & 15)];
            acc[q] = (f32x4){bv, bv, bv, bv};
        }
#pragma unroll
        for (int kt = 0; kt < 8; kt++) {
            bf16x8 a = *(const bf16x8*)&s_x1[(lane & 15) * 264 + kt * 32 + (lane >> 4) * 8];
#pragma unroll
            for (int q = 0; q < 4; q++) {
                int nt = w * 4 + q;
                bf16x8 b;
                if (PACKED) b = wp[(kt * 16 + nt) * 64 + lane];
                else        b = load_bfrag(wx2, 256, kt, nt, lane);
                acc[q] = __builtin_amdgcn_mfma_f32_16x16x32_bf16(a, b, acc[q], 0, 0, 0);
            }
        }
#pragma unroll
        for (int q = 0; q < 4; q++) {
            int nt = w * 4 + q;
#pragma unroll
            for (int r = 0; r < 4; r++) {
                int m = (lane >> 4) * 4 + r;
                s_x2[m * 264 + nt * 16 + (lane & 15)] = f2bf(acc[q][r]);
            }
        }
    }
    __syncthreads();

    // ---- Phase F: fts_X = X2 @ fts_cat  +  depthwise (VALU) ----
    {
        const int c  = t & 127;
        const int mg = t >> 7;
        float wd[64];
#pragma unroll
        for (int q = 0; q < 16; q++) {
            float4 v = *(const float4*)&wdw[c * 64 + q * 4];
            wd[q * 4 + 0] = v.x; wd[q * 4 + 1] = v.y;
            wd[q * 4 + 2] = v.z; wd[q * 4 + 3] = v.w;
        }
        float bd[4];
#pragma unroll
        for (int d = 0; d < 4; d++) bd[d] = bdw[c * 4 + d];
#pragma unroll 1
        for (int ml = 0; ml < 8; ml++) {
            int m  = mg * 8 + ml;
            int gp = gp0 + m;
            float fc[16];
            if (c < 64) {
#pragma unroll
                for (int j = 0; j < 16; j++) fc[j] = bf2f(s_h2[(m * 16 + j) * 64 + c]);
            } else {
#pragma unroll
                for (int j = 0; j < 16; j++) fc[j] = fts[(gp * 16 + j) * 64 + (c - 64)];
            }
            float fXr[16];
#pragma unroll
            for (int i = 0; i < 16; i++) {
                float a = 0.f;
#pragma unroll
                for (int jj = 0; jj < 2; jj++) {
                    uint4 xv = *(const uint4*)&s_x2[m * 264 + i * 16 + jj * 8];
                    a = fmaf(__uint_as_float(xv.x << 16),          fc[jj * 8 + 0], a);
                    a = fmaf(__uint_as_float(xv.x & 0xFFFF0000u),  fc[jj * 8 + 1], a);
                    a = fmaf(__uint_as_float(xv.y << 16),          fc[jj * 8 + 2], a);
                    a = fmaf(__uint_as_float(xv.y & 0xFFFF0000u),  fc[jj * 8 + 3], a);
                    a = fmaf(__uint_as_float(xv.z << 16),          fc[jj * 8 + 4], a);
                    a = fmaf(__uint_as_float(xv.z & 0xFFFF0000u),  fc[jj * 8 + 5], a);
                    a = fmaf(__uint_as_float(xv.w << 16),          fc[jj * 8 + 6], a);
                    a = fmaf(__uint_as_float(xv.w & 0xFFFF0000u),  fc[jj * 8 + 7], a);
                }
                fXr[i] = a;
            }
            ushort4 dv;
            {
                float o[4];
#pragma unroll
                for (int d = 0; d < 4; d++) {
                    float a = bd[d];
#pragma unroll
                    for (int k = 0; k < 16; k++) a = fmaf(fXr[k], wd[d * 16 + k], a);
                    o[d] = a;
                }
                dv.x = f2bf(o[0]); dv.y = f2bf(o[1]); dv.z = f2bf(o[2]); dv.w = f2bf(o[3]);
            }
            *(ushort4*)&s_dw[m * 520 + c * 4] = dv;
        }
    }
    __syncthreads();

    // ---- Phase G: y = BN(elu(dw @ wpw + bpw)), MFMA M=16,N=128,K=512 ----
    {
        const bf16x8* wp = (const bf16x8*)wpack + 16896;  // wpw
        f32x4 acc[2];
#pragma unroll
        for (int q = 0; q < 2; q++) {
            float bv = bpw[(w * 2 + q) * 16 + (lane & 15)];
            acc[q] = (f32x4){bv, bv, bv, bv};
        }
#pragma unroll
        for (int kt = 0; kt < 16; kt++) {
            bf16x8 a = *(const bf16x8*)&s_dw[(lane & 15) * 520 + kt * 32 + (lane >> 4) * 8];
#pragma unroll
            for (int q = 0; q < 2; q++) {
                int nt = w * 2 + q;
                bf16x8 b;
                if (PACKED) b = wp[(kt * 8 + nt) * 64 + lane];
                else        b = load_bfrag(wpw, 128, kt, nt, lane);
                acc[q] = __builtin_amdgcn_mfma_f32_16x16x32_bf16(a, b, acc[q], 0, 0, 0);
            }
        }
#pragma unroll
        for (int q = 0; q < 2; q++) {
            int co = (w * 2 + q) * 16 + (lane & 15);
            float scale = bn_gamma[co] * rsqrtf(bn_var[co] + 1e-5f);
            float shift = bn_beta[co] - bn_mean[co] * scale;
#pragma unroll
            for (int r = 0; r < 4; r++) {
                int m = (lane >> 4) * 4 + r;
                out[(gp0 + m) * 128 + co] = fmaf(elu_f(acc[q][r]), scale, shift);
            }
        }
    }
}

extern "C" void kernel_launch(void* const* d_in, const int* in_sizes, int n_in,
                              void* d_out, int out_size, void* d_ws, size_t ws_size,
                              hipStream_t stream) {
    const float* rep_pt   = (const float*)d_in[0];
    const float* pts      = (const float*)d_in[1];
    const float* fts      = (const float*)d_in[2];
    const float* w1       = (const float*)d_in[3];
    const float* b1       = (const float*)d_in[4];
    const float* w2       = (const float*)d_in[5];
    const float* b2       = (const float*)d_in[6];
    const float* wc1      = (const float*)d_in[7];
    const float* bc1      = (const float*)d_in[8];
    const float* wx1      = (const float*)d_in[9];
    const float* bx1      = (const float*)d_in[10];
    const float* wx2      = (const float*)d_in[11];
    const float* bx2      = (const float*)d_in[12];
    const float* wdw      = (const float*)d_in[13];
    const float* bdw      = (const float*)d_in[14];
    const float* wpw      = (const float*)d_in[15];
    const float* bpw      = (const float*)d_in[16];
    const float* bn_gamma = (const float*)d_in[17];
    const float* bn_beta  = (const float*)d_in[18];
    const float* bn_mean  = (const float*)d_in[19];
    const float* bn_var   = (const float*)d_in[20];
    float* out = (float*)d_out;

    const bool packed = (d_ws != nullptr) && (ws_size >= (size_t)WS_NEEDED);
    unsigned short* wpack = (unsigned short*)d_ws;

    if (packed) {
        pack_weights<<<98, 256, 0, stream>>>(w2, wx1, wx2, wpw, wpack);
        xconv_main<true><<<NPTS / MPB, NTHR, 0, stream>>>(
            rep_pt, pts, fts, w1, b1, w2, b2, wc1, bc1, wx1, bx1, wx2, bx2,
            wdw, bdw, wpw, bpw, bn_gamma, bn_beta, bn_mean, bn_var, wpack, out);
    } else {
        xconv_main<false><<<NPTS / MPB, NTHR, 0, stream>>>(
            rep_pt, pts, fts, w1, b1, w2, b2, wc1, bc1, wx1, bx1, wx2, bx2,
            wdw, bdw, wpw, bpw, bn_gamma, bn_beta, bn_mean, bn_var, (const unsigned short*)nullptr, out);
    }
}